// Round 14
// baseline (37.736 us; speedup 1.0000x reference)
//
#include <hip/hip_runtime.h>
#include <math.h>

#define B_ 8
#define S_ 2048
#define D_ 128
#define K_ 64
#define SIG_ 0.5f
#define EPS_ 10.0f
#define E_ 2.718281828459045f

#define AL(p) __hip_atomic_load((p), __ATOMIC_RELAXED, __HIP_MEMORY_SCOPE_AGENT)
#define AS(p, v) __hip_atomic_store((p), (v), __ATOMIC_RELAXED, __HIP_MEMORY_SCOPE_AGENT)

// XCD-aware work remap (bijective on [0,512)): batch = bx&7 == XCD id.
__device__ __forceinline__ int remap512(int bx) {
    return ((bx & 7) << 6) | (bx >> 3);
}

// ---------------- K1: grid = 512 + 8 blocks.
// Blocks 0..511: per (b,k) class stats (R6-proven ballot+gather); b==0 blocks
// also write csqK[k]; block 0 zeroes k3's counter tree (plain stores, visible
// across the dispatch boundary).
// Blocks 512..519: per-batch totals fsumA[b,:] / ssumA[b] straight from F
// (label-independent), removing that work from all 512 k3 blocks.
__global__ void __launch_bounds__(256) k1_stats(
    const float* __restrict__ F, const float* __restrict__ C,
    const int* __restrict__ L,
    float* __restrict__ fsumK, float* __restrict__ ssumK, float* __restrict__ cntK,
    float* __restrict__ csqK, float* __restrict__ fsumA, float* __restrict__ ssumA,
    int* __restrict__ cnts) {

    __shared__ float redF[4][128];
    __shared__ float redS[4];
    __shared__ int   redC[4];
    __shared__ float4 redQ[256];

    int tid = threadIdx.x;

    if (blockIdx.x >= 512) {
        // ---- per-batch totals: 1 block per batch, float4 streaming
        int b = blockIdx.x - 512;
        int d4 = tid & 31, rg = tid >> 5;            // 8 row-groups of 256 rows
        const float4* Fb4 = (const float4*)(F + (size_t)b * S_ * D_);
        const float4* p = Fb4 + (size_t)(rg * 256) * 32 + d4;
        float4 s; s.x = s.y = s.z = s.w = 0.f;
        float r2 = 0.f;
        #pragma unroll 8
        for (int r = 0; r < 256; ++r) {
            float4 v = p[(size_t)r * 32];
            s.x += v.x; s.y += v.y; s.z += v.z; s.w += v.w;
            r2 = fmaf(v.x, v.x, fmaf(v.y, v.y, fmaf(v.z, v.z, fmaf(v.w, v.w, r2))));
        }
        redQ[tid] = s;
        ((float*)redF)[tid] = r2;
        __syncthreads();
        if (tid < 32) {
            float4 a; a.x = a.y = a.z = a.w = 0.f;
            #pragma unroll
            for (int g = 0; g < 8; ++g) {
                float4 v = redQ[g * 32 + tid];
                a.x += v.x; a.y += v.y; a.z += v.z; a.w += v.w;
            }
            ((float4*)(fsumA + (size_t)b * D_))[tid] = a;
        }
        if (tid < 64) {
            const float* fr = (const float*)redF;
            float v = fr[tid] + fr[tid + 64] + fr[tid + 128] + fr[tid + 192];
            #pragma unroll
            for (int m = 1; m < 64; m <<= 1) v += __shfl_xor(v, m);
            if (tid == 0) ssumA[b] = v;
        }
        return;
    }

    int bx = remap512(blockIdx.x);
    int k = bx & (K_ - 1);
    int b = bx >> 6;
    int lane = tid & 63;
    int wv = tid >> 6;

    const int* Lb = L + b * S_;
    const float* Fb = F + (size_t)b * S_ * D_;

    float a0 = 0.f, a1 = 0.f, q0 = 0.f, q1 = 0.f;
    int cnt = 0;
    #pragma unroll
    for (int rr = 0; rr < 8; ++rr) {
        int r = (wv << 3) + rr;
        int lbl = Lb[(r << 6) + lane];
        unsigned long long m = __ballot(lbl == k);
        cnt += (int)__popcll(m);
        while (m) {               // wave-uniform trip count (~1 per round)
            int i = __ffsll((long long)m) - 1;
            m &= m - 1;
            const float* row = Fb + (size_t)((r << 6) + i) * D_;
            float v0 = row[lane];
            float v1 = row[64 + lane];
            a0 += v0; q0 = fmaf(v0, v0, q0);
            a1 += v1; q1 = fmaf(v1, v1, q1);
        }
    }
    float qq = q0 + q1;
    #pragma unroll
    for (int m = 1; m < 64; m <<= 1) qq += __shfl_xor(qq, m);
    redF[wv][lane] = a0;
    redF[wv][64 + lane] = a1;
    if (lane == 0) { redS[wv] = qq; redC[wv] = cnt; }
    __syncthreads();

    if (tid < 128) {
        float s = (redF[0][tid] + redF[1][tid]) + (redF[2][tid] + redF[3][tid]);
        fsumK[(size_t)bx * D_ + tid] = s;
    }
    if (tid == 0) {
        ssumK[bx] = (redS[0] + redS[1]) + (redS[2] + redS[3]);
        cntK[bx] = (float)(redC[0] + redC[1] + redC[2] + redC[3]);
    }
    if (b == 0 && wv == 0) {          // csqK[k], once per k
        float x0 = C[(k << 7) + lane];
        float x1 = C[(k << 7) + 64 + lane];
        float cs = fmaf(x0, x0, x1 * x1);
        #pragma unroll
        for (int m = 1; m < 64; m <<= 1) cs += __shfl_xor(cs, m);
        if (lane == 0) csqK[k] = cs;
    }
    if (blockIdx.x == 0 && tid < 17) cnts[tid * 16] = 0;  // tree counters
}

// ---------------- K3: main per-anchor kernel; 16-leaf tree finish + out
// grid = 512 blocks x 256 threads; each wave handles one octet (8 anchors)
__global__ void __launch_bounds__(256) k3_main(
    const float* __restrict__ F, const float* __restrict__ C,
    const float* __restrict__ phi, const int* __restrict__ L,
    const float* __restrict__ fsumK, const float* __restrict__ ssumK,
    const float* __restrict__ cntK, const float* __restrict__ csqK,
    const float* __restrict__ fsumA, const float* __restrict__ ssumA,
    float* __restrict__ partial, int* __restrict__ cnts,
    float* __restrict__ out) {

    __shared__ float Cs[K_ * 129];
    __shared__ float wacc[4];
    __shared__ int isLast;
    int tid = threadIdx.x;
    int bxw = remap512(blockIdx.x);
    int b = bxw >> 6;

    {   // stage centroids (only per-block staging left)
        const float4* C4 = (const float4*)C;
        #pragma unroll
        for (int it = 0; it < 8; ++it) {
            int i = it * 256 + tid;
            float4 v = C4[i];
            float* p = &Cs[(i >> 5) * 129 + ((i & 31) << 2)];
            p[0] = v.x; p[1] = v.y; p[2] = v.z; p[3] = v.w;
        }
    }
    __syncthreads();

    int lane = tid & 63;
    int wv = tid >> 6;

    float csq = csqK[lane];
    float phv = phi[lane];
    float ssl = ssumK[b * K_ + lane];
    float cnl = cntK[b * K_ + lane];
    float ssA = ssumA[b];

    int wid = __builtin_amdgcn_readfirstlane(tid) >> 6;
    int o = bxw * 4 + wid;
    int a0g = o * 8;
    const float4* F4 = (const float4*)F;

    // ---- phase A: per-anchor sq / dot(fsumK[lbl]) / dot(fsumA); 8 lanes/anchor
    int j_of = lane >> 3, q = lane & 7;
    int a_mine = a0g + j_of;
    int lbl_p = L[a_mine];
    const float4* fr = F4 + (size_t)a_mine * 32;
    const float4* fk = (const float4*)(fsumK + (size_t)(b * K_ + lbl_p) * D_);
    const float4* fa4 = (const float4*)(fsumA + (size_t)b * D_);

    float sq_p = 0.f, dk_p = 0.f, da_p = 0.f;
    #pragma unroll
    for (int i = 0; i < 4; ++i) {
        int dq = i * 8 + q;
        float4 fv = fr[dq];
        float4 kv = fk[dq];
        float4 av = fa4[dq];
        sq_p = fmaf(fv.x, fv.x, fmaf(fv.y, fv.y, fmaf(fv.z, fv.z, fmaf(fv.w, fv.w, sq_p))));
        dk_p = fmaf(fv.x, kv.x, fmaf(fv.y, kv.y, fmaf(fv.z, kv.z, fmaf(fv.w, kv.w, dk_p))));
        da_p = fmaf(fv.x, av.x, fmaf(fv.y, av.y, fmaf(fv.z, av.z, fmaf(fv.w, av.w, da_p))));
    }
    #pragma unroll
    for (int m = 1; m < 8; m <<= 1) {
        sq_p += __shfl_xor(sq_p, m);
        dk_p += __shfl_xor(dk_p, m);
        da_p += __shfl_xor(da_p, m);
    }

    // ---- phase B: centroid dots, lane = k, wave-uniform F loads (R6 form)
    float facc[8];
    #pragma unroll
    for (int j = 0; j < 8; ++j) facc[j] = 0.f;

    float4 fw[8], fwn[8];
    #pragma unroll
    for (int j = 0; j < 8; ++j) fw[j] = F4[(size_t)(a0g + j) * 32 + 0];

    for (int dq = 0; dq < 32; ++dq) {
        if (dq < 31) {
            #pragma unroll
            for (int j = 0; j < 8; ++j) fwn[j] = F4[(size_t)(a0g + j) * 32 + dq + 1];
        }
        int cbase = lane * 129 + (dq << 2);
        #pragma unroll
        for (int l = 0; l < 4; ++l) {
            float cs = Cs[cbase + l];
            #pragma unroll
            for (int j = 0; j < 8; ++j) {
                float fe = (l == 0) ? fw[j].x : (l == 1) ? fw[j].y : (l == 2) ? fw[j].z : fw[j].w;
                facc[j] = fmaf(fe, cs, facc[j]);
            }
        }
        #pragma unroll
        for (int j = 0; j < 8; ++j) fw[j] = fwn[j];
    }

    // ---- phase C: per-anchor scalar epilogue
    float acc = 0.f;
    #pragma unroll
    for (int j = 0; j < 8; ++j) {
        float sq_j = __shfl(sq_p, j * 8);
        float dk_j = __shfl(dk_p, j * 8);
        float da_j = __shfl(da_p, j * 8);
        int lbl_j = __shfl(lbl_p, j * 8);
        float cnt_j = __shfl(cnl, lbl_j);
        float ssm_j = __shfl(ssl, lbl_j);

        float cd2 = (sq_j + csq - 2.f * facc[j]) * (1.f / D_);
        cd2 = fmaxf(cd2, 0.f) / phv;

        float s_cd = cd2;
        #pragma unroll
        for (int m = 1; m < 64; m <<= 1) s_cd += __shfl_xor(s_cd, m);
        float pos_cent = __shfl(cd2, lbl_j);

        float ncx = (s_cd - pos_cent) * (1.f / (K_ - 1));
        float S_same = (cnt_j * sq_j + ssm_j - 2.f * dk_j) * (1.f / D_);
        float S_all = ((float)S_ * sq_j + ssA - 2.f * da_j) * (1.f / D_);
        float pos_x = fmaxf(S_same, 0.f) / fmaxf(cnt_j - 1.f, 1.f);
        float neg_cnt = (float)S_ - cnt_j;
        float neg_x = fmaxf(S_all - S_same, 0.f) / fmaxf(neg_cnt, 1.f);

        float neg_sup = neg_x * __logf(neg_x + E_);
        float ncl = ncx * __logf(ncx + E_);

        float pa = SIG_ * pos_x + (1.f - SIG_) * pos_cent
                 - (SIG_ * neg_sup + (1.f - SIG_) * ncl) + EPS_;
        if (neg_cnt > 0.5f) acc += pa;
    }

    if (lane == 0) wacc[wid] = acc;
    __syncthreads();

    // ---- 16-leaf tree finish (leaves on distinct cache lines -> parallel)
    if (tid == 0) {
        float blk = wacc[0] + wacc[1] + wacc[2] + wacc[3];
        AS(&partial[bxw], blk);
        int leaf = bxw & 15;
        int old = __hip_atomic_fetch_add(&cnts[leaf * 16], 1, __ATOMIC_ACQ_REL,
                                         __HIP_MEMORY_SCOPE_AGENT);
        int fin = 0;
        if (old == 32 - 1) {          // 512 blocks / 16 leaves
            int r = __hip_atomic_fetch_add(&cnts[256], 1, __ATOMIC_ACQ_REL,
                                           __HIP_MEMORY_SCOPE_AGENT);
            fin = (r == 15);
        }
        isLast = fin;
    }
    __syncthreads();
    if (isLast) {
        float v = 0.f;
        for (int i = tid; i < 512; i += 256) v += AL(&partial[i]);
        #pragma unroll
        for (int m = 1; m < 64; m <<= 1) v += __shfl_xor(v, m);
        if (lane == 0) wacc[wv] = v;
        __syncthreads();
        if (tid == 0) out[0] = (wacc[0] + wacc[1] + wacc[2] + wacc[3]) * (1.0f / (float)S_);
    }
}

extern "C" void kernel_launch(void* const* d_in, const int* in_sizes, int n_in,
                              void* d_out, int out_size, void* d_ws, size_t ws_size,
                              hipStream_t stream) {
    const float* F = (const float*)d_in[0];    // [B,S,D]
    const float* C = (const float*)d_in[1];    // [K,D]
    const float* phi = (const float*)d_in[2];  // [K]
    const int* L = (const int*)d_in[3];        // [B,S]
    float* out = (float*)d_out;

    float* ws = (float*)d_ws;
    float* fsumK = ws;                                // B*K*D = 65536
    float* ssumK = fsumK + (size_t)B_ * K_ * D_;      // 512
    float* cntK  = ssumK + B_ * K_;                   // 512
    float* csqK  = cntK + B_ * K_;                    // 64
    float* fsumA = csqK + K_;                         // B*D = 1024
    float* ssumA = fsumA + B_ * D_;                   // 8
    float* partial = ssumA + B_;                      // 512
    int* cnts = (int*)(partial + 512);                // 16 leaves*16 + root at 256

    k1_stats<<<B_ * K_ + B_, 256, 0, stream>>>(F, C, L, fsumK, ssumK, cntK,
                                               csqK, fsumA, ssumA, cnts);
    k3_main<<<512, 256, 0, stream>>>(F, C, phi, L, fsumK, ssumK, cntK, csqK,
                                     fsumA, ssumA, partial, cnts, out);
}

// Round 15
// 26.997 us; speedup vs baseline: 1.3978x; 1.3978x over previous
//
#include <hip/hip_runtime.h>
#include <math.h>

#define B_ 8
#define S_ 2048
#define D_ 128
#define K_ 64
#define SIG_ 0.5f
#define EPS_ 10.0f
#define E_ 2.718281828459045f

// XCD-aware remaps: HW round-robins blockIdx over 8 XCDs; batch == XCD.
__device__ __forceinline__ int remap512(int bx) { return ((bx & 7) << 6) | (bx >> 3); }
__device__ __forceinline__ int remap256(int bx) { return ((bx & 7) << 5) | (bx >> 3); }

// ---------------- K1: per (b,k) class stats, 4-wave ballot + immediate gather
// (R13-proven) + csqK precompute on b==0 blocks.
__global__ void __launch_bounds__(256) k1_stats(
    const float* __restrict__ F, const float* __restrict__ C,
    const int* __restrict__ L,
    float* __restrict__ fsumK, float* __restrict__ ssumK, float* __restrict__ cntK,
    float* __restrict__ csqK) {
    int bx = remap512(blockIdx.x);
    int k = bx & (K_ - 1);
    int b = bx >> 6;
    int tid = threadIdx.x;
    int lane = tid & 63;
    int wv = tid >> 6;

    __shared__ float redF[4][128];
    __shared__ float redS[4];
    __shared__ int   redC[4];

    const int* Lb = L + b * S_;
    const float* Fb = F + (size_t)b * S_ * D_;

    float a0 = 0.f, a1 = 0.f, q0 = 0.f, q1 = 0.f;
    int cnt = 0;
    #pragma unroll
    for (int rr = 0; rr < 8; ++rr) {
        int r = (wv << 3) + rr;
        int lbl = Lb[(r << 6) + lane];
        unsigned long long m = __ballot(lbl == k);
        cnt += (int)__popcll(m);
        while (m) {               // wave-uniform trip count (~1 per round)
            int i = __ffsll((long long)m) - 1;
            m &= m - 1;
            const float* row = Fb + (size_t)((r << 6) + i) * D_;
            float v0 = row[lane];
            float v1 = row[64 + lane];
            a0 += v0; q0 = fmaf(v0, v0, q0);
            a1 += v1; q1 = fmaf(v1, v1, q1);
        }
    }
    float qq = q0 + q1;
    #pragma unroll
    for (int m = 1; m < 64; m <<= 1) qq += __shfl_xor(qq, m);
    redF[wv][lane] = a0;
    redF[wv][64 + lane] = a1;
    if (lane == 0) { redS[wv] = qq; redC[wv] = cnt; }
    __syncthreads();

    if (tid < 128) {
        float s = (redF[0][tid] + redF[1][tid]) + (redF[2][tid] + redF[3][tid]);
        fsumK[(size_t)bx * D_ + tid] = s;
    }
    if (tid == 0) {
        ssumK[bx] = (redS[0] + redS[1]) + (redS[2] + redS[3]);
        cntK[bx] = (float)(redC[0] + redC[1] + redC[2] + redC[3]);
    }
    if (b == 0 && wv == 0) {          // csqK[k], once per k
        float x0 = C[(k << 7) + lane];
        float x1 = C[(k << 7) + 64 + lane];
        float cs = fmaf(x0, x0, x1 * x1);
        #pragma unroll
        for (int m = 1; m < 64; m <<= 1) cs += __shfl_xor(cs, m);
        if (lane == 0) csqK[k] = cs;
    }
}

// ---------------- K3: main per-anchor kernel, 512-thread blocks (8 waves),
// grid = 256; each wave handles one octet (per-wave work identical to R13,
// but Cs/Fa staging + prologue/epilogue amortized over 2x waves).
__global__ void __launch_bounds__(512) k3_main(
    const float* __restrict__ F, const float* __restrict__ C,
    const float* __restrict__ phi, const int* __restrict__ L,
    const float* __restrict__ fsumK, const float* __restrict__ ssumK,
    const float* __restrict__ cntK, const float* __restrict__ csqK,
    float* __restrict__ partial) {

    __shared__ float Cs[K_ * 129];
    __shared__ float4 redA[256];
    __shared__ float Fa[D_];
    __shared__ float wacc[8];
    int tid = threadIdx.x;
    int bxw = remap256(blockIdx.x);
    int b = bxw >> 5;                 // 32 blocks per batch; == blockIdx.x & 7

    {   // stage centroids: 2048 float4s over 512 threads (4 iters)
        const float4* C4 = (const float4*)C;
        #pragma unroll
        for (int it = 0; it < 4; ++it) {
            int i = it * 512 + tid;
            float4 v = C4[i];
            float* p = &Cs[(i >> 5) * 129 + ((i & 31) << 2)];
            p[0] = v.x; p[1] = v.y; p[2] = v.z; p[3] = v.w;
        }
    }
    if (tid < 256) {   // Fa[d] = sum_k fsumK[b,k,d]
        int d4 = tid & 31, kg = tid >> 5;
        const float4* g4 = (const float4*)(fsumK + (size_t)b * K_ * D_) + (size_t)kg * 8 * 32 + d4;
        float4 s; s.x = s.y = s.z = s.w = 0.f;
        #pragma unroll
        for (int kk = 0; kk < 8; ++kk) {
            float4 v = g4[(size_t)kk * 32];
            s.x += v.x; s.y += v.y; s.z += v.z; s.w += v.w;
        }
        redA[tid] = s;
    }
    __syncthreads();
    if (tid < 32) {
        float4 a; a.x = a.y = a.z = a.w = 0.f;
        #pragma unroll
        for (int g = 0; g < 8; ++g) {
            float4 v = redA[g * 32 + tid];
            a.x += v.x; a.y += v.y; a.z += v.z; a.w += v.w;
        }
        ((float4*)Fa)[tid] = a;
    }
    __syncthreads();

    int lane = tid & 63;

    float csq = csqK[lane];           // precomputed in k1
    float phv = phi[lane];
    float ssl = ssumK[b * K_ + lane];
    float cnl = cntK[b * K_ + lane];
    float ssA = ssl;
    #pragma unroll
    for (int m = 1; m < 64; m <<= 1) ssA += __shfl_xor(ssA, m);

    int wid = __builtin_amdgcn_readfirstlane(tid) >> 6;   // SGPR wave id 0..7
    int o = bxw * 8 + wid;
    int a0g = o * 8;
    const float4* F4 = (const float4*)F;

    // ---- phase A: per-anchor sq / dot(fsumK[lbl]) / dot(Fa); 8 lanes/anchor
    int j_of = lane >> 3, q = lane & 7;
    int a_mine = a0g + j_of;
    int lbl_p = L[a_mine];
    const float4* fr = F4 + (size_t)a_mine * 32;
    const float4* fk = (const float4*)(fsumK + (size_t)(b * K_ + lbl_p) * D_);
    const float4* fa4 = (const float4*)Fa;

    float sq_p = 0.f, dk_p = 0.f, da_p = 0.f;
    #pragma unroll
    for (int i = 0; i < 4; ++i) {
        int dq = i * 8 + q;
        float4 fv = fr[dq];
        float4 kv = fk[dq];
        float4 av = fa4[dq];
        sq_p = fmaf(fv.x, fv.x, fmaf(fv.y, fv.y, fmaf(fv.z, fv.z, fmaf(fv.w, fv.w, sq_p))));
        dk_p = fmaf(fv.x, kv.x, fmaf(fv.y, kv.y, fmaf(fv.z, kv.z, fmaf(fv.w, kv.w, dk_p))));
        da_p = fmaf(fv.x, av.x, fmaf(fv.y, av.y, fmaf(fv.z, av.z, fmaf(fv.w, av.w, da_p))));
    }
    #pragma unroll
    for (int m = 1; m < 8; m <<= 1) {
        sq_p += __shfl_xor(sq_p, m);
        dk_p += __shfl_xor(dk_p, m);
        da_p += __shfl_xor(da_p, m);
    }

    // ---- phase B: centroid dots, lane = k, wave-uniform F loads (R13 form)
    float facc[8];
    #pragma unroll
    for (int j = 0; j < 8; ++j) facc[j] = 0.f;

    float4 fw[8], fwn[8];
    #pragma unroll
    for (int j = 0; j < 8; ++j) fw[j] = F4[(size_t)(a0g + j) * 32 + 0];

    for (int dq = 0; dq < 32; ++dq) {
        if (dq < 31) {
            #pragma unroll
            for (int j = 0; j < 8; ++j) fwn[j] = F4[(size_t)(a0g + j) * 32 + dq + 1];
        }
        int cbase = lane * 129 + (dq << 2);
        #pragma unroll
        for (int l = 0; l < 4; ++l) {
            float cs = Cs[cbase + l];
            #pragma unroll
            for (int j = 0; j < 8; ++j) {
                float fe = (l == 0) ? fw[j].x : (l == 1) ? fw[j].y : (l == 2) ? fw[j].z : fw[j].w;
                facc[j] = fmaf(fe, cs, facc[j]);
            }
        }
        #pragma unroll
        for (int j = 0; j < 8; ++j) fw[j] = fwn[j];
    }

    // ---- phase C: per-anchor scalar epilogue
    float acc = 0.f;
    #pragma unroll
    for (int j = 0; j < 8; ++j) {
        float sq_j = __shfl(sq_p, j * 8);
        float dk_j = __shfl(dk_p, j * 8);
        float da_j = __shfl(da_p, j * 8);
        int lbl_j = __shfl(lbl_p, j * 8);
        float cnt_j = __shfl(cnl, lbl_j);
        float ssm_j = __shfl(ssl, lbl_j);

        float cd2 = (sq_j + csq - 2.f * facc[j]) * (1.f / D_);
        cd2 = fmaxf(cd2, 0.f) / phv;

        float s_cd = cd2;
        #pragma unroll
        for (int m = 1; m < 64; m <<= 1) s_cd += __shfl_xor(s_cd, m);
        float pos_cent = __shfl(cd2, lbl_j);

        float ncx = (s_cd - pos_cent) * (1.f / (K_ - 1));
        float S_same = (cnt_j * sq_j + ssm_j - 2.f * dk_j) * (1.f / D_);
        float S_all = ((float)S_ * sq_j + ssA - 2.f * da_j) * (1.f / D_);
        float pos_x = fmaxf(S_same, 0.f) / fmaxf(cnt_j - 1.f, 1.f);
        float neg_cnt = (float)S_ - cnt_j;
        float neg_x = fmaxf(S_all - S_same, 0.f) / fmaxf(neg_cnt, 1.f);

        float neg_sup = neg_x * __logf(neg_x + E_);
        float ncl = ncx * __logf(ncx + E_);

        float pa = SIG_ * pos_x + (1.f - SIG_) * pos_cent
                 - (SIG_ * neg_sup + (1.f - SIG_) * ncl) + EPS_;
        if (neg_cnt > 0.5f) acc += pa;
    }

    if (lane == 0) wacc[wid] = acc;
    __syncthreads();

    // plain-store finish (no atomics) — proven in R13
    if (tid == 0) {
        float s = 0.f;
        #pragma unroll
        for (int w = 0; w < 8; ++w) s += wacc[w];
        partial[bxw] = s;
    }
}

// ---------------- K4: 1-block final reduce (256 partials)
__global__ void __launch_bounds__(256) k4_reduce(
    const float* __restrict__ partial, float* __restrict__ out) {
    int tid = threadIdx.x;
    int lane = tid & 63;
    int wv = tid >> 6;
    __shared__ float w[4];
    float v = partial[tid];
    #pragma unroll
    for (int m = 1; m < 64; m <<= 1) v += __shfl_xor(v, m);
    if (lane == 0) w[wv] = v;
    __syncthreads();
    if (tid == 0) out[0] = (w[0] + w[1] + w[2] + w[3]) * (1.0f / (float)S_);
}

extern "C" void kernel_launch(void* const* d_in, const int* in_sizes, int n_in,
                              void* d_out, int out_size, void* d_ws, size_t ws_size,
                              hipStream_t stream) {
    const float* F = (const float*)d_in[0];    // [B,S,D]
    const float* C = (const float*)d_in[1];    // [K,D]
    const float* phi = (const float*)d_in[2];  // [K]
    const int* L = (const int*)d_in[3];        // [B,S]
    float* out = (float*)d_out;

    float* ws = (float*)d_ws;
    float* fsumK = ws;                                // B*K*D = 65536
    float* ssumK = fsumK + (size_t)B_ * K_ * D_;      // 512
    float* cntK  = ssumK + B_ * K_;                   // 512
    float* csqK  = cntK + B_ * K_;                    // 64
    float* partial = csqK + K_;                       // 256

    k1_stats<<<B_ * K_, 256, 0, stream>>>(F, C, L, fsumK, ssumK, cntK, csqK);
    k3_main<<<256, 512, 0, stream>>>(F, C, phi, L, fsumK, ssumK, cntK, csqK, partial);
    k4_reduce<<<1, 256, 0, stream>>>(partial, out);
}